// Round 5
// baseline (565.238 us; speedup 1.0000x reference)
//
#include <hip/hip_runtime.h>
#include <hip/hip_bf16.h>
#include <math.h>

// Problem constants (Qwen2MoeAttention, T=2048)
#define TSEQ   2048
#define HID    2048
#define NH     16
#define NKV    4
#define HD     128
#define KVD    512
#define SCALING 0.08838834764831845f   // 1/sqrt(128)
#define LOG2_ROPE_BASE 19.931568569324174f  // log2(1e6)
#define LOG2E  1.4426950408889634f

typedef float f4  __attribute__((ext_vector_type(4),  aligned(16)));
typedef float f16v __attribute__((ext_vector_type(16), aligned(64)));
typedef short s8v __attribute__((ext_vector_type(8),  aligned(16)));
typedef short s4v __attribute__((ext_vector_type(4),  aligned(8)));

__device__ __forceinline__ short f2bf(float x) {
    union { __hip_bfloat16 b; short s; } u;
    u.b = __float2bfloat16(x);
    return u.s;
}
__device__ __forceinline__ unsigned pk2(float a, float b) {
    return ((unsigned)(unsigned short)f2bf(b) << 16) | (unsigned)(unsigned short)f2bf(a);
}

// ---------------------------------------------------------------------------
// f32 -> bf16 bulk convert (hidden_states), 8 elems/thread
// ---------------------------------------------------------------------------
__global__ __launch_bounds__(256) void f32_to_bf16(
    const float* __restrict__ in, short* __restrict__ out)
{
    const int i = (blockIdx.x * 256 + threadIdx.x) * 8;
    f4 a = *(const f4*)(in + i);
    f4 b = *(const f4*)(in + i + 4);
    s8v v;
    v[0] = f2bf(a[0]); v[1] = f2bf(a[1]); v[2] = f2bf(a[2]); v[3] = f2bf(a[3]);
    v[4] = f2bf(b[0]); v[5] = f2bf(b[1]); v[6] = f2bf(b[2]); v[7] = f2bf(b[3]);
    *(s8v*)(out + i) = v;
}

// ---------------------------------------------------------------------------
// MFMA GPTQ GEMM (16x16x32). MODE 0: f32 row-major out. MODE 1: bf16
// transposed out (Vt[col][T] for attention's V^T operand).
// ---------------------------------------------------------------------------
template<int BM, int BN, int MODE>
__global__ __launch_bounds__(256) void gemm_gptq_mfma(
    const short* __restrict__ X, const int* __restrict__ qw,
    const float* __restrict__ scales, const int* __restrict__ zeros,
    void* __restrict__ Yv, int OUT)
{
    constexpr int WM = BM / 2, WN = BN / 2, FM = WM / 16, FN = WN / 16;
    __shared__ __align__(16) short As[BM * 64];
    __shared__ __align__(16) short Bs[BN * 64];
    const int tid = threadIdx.x;
    const int l = tid & 63, w = tid >> 6;
    const int l15 = l & 15, l4 = l >> 4;
    const int wr = w >> 1, wc = w & 1;
    const int br = blockIdx.y, bc = blockIdx.x;

    const int colB = tid % BN;
    const int colg = bc * BN + colB;
    const int prb  = (tid / BN) * (BN / 32);

    f4 acc[FM][FN] = {};

    for (int kt = 0; kt < 32; ++kt) {
        __syncthreads();
        #pragma unroll
        for (int n = 0; n < BM / 32; ++n) {
            int f = tid + 256 * n;
            int r = f >> 3, c8 = f & 7;
            s8v av = *(const s8v*)(X + (size_t)(br * BM + r) * 2048 + kt * 64 + c8 * 8);
            *(s8v*)(&As[r * 64 + ((c8 * 8) ^ ((r & 7) << 3))]) = av;
        }
        {
            const int g = kt >> 1;
            const float sc = scales[g * OUT + colg];
            const float zf = (float)zeros[g * OUT + colg];
            #pragma unroll
            for (int n = 0; n < BN / 32; ++n) {
                int pr = prb + n;
                unsigned p = (unsigned)qw[(kt * 8 + pr) * OUT + colg];
                s8v bv;
                #pragma unroll
                for (int s = 0; s < 8; ++s) {
                    float qv = (float)((p >> (4 * s)) & 15u);
                    bv[s] = f2bf((qv - zf) * sc);
                }
                *(s8v*)(&Bs[colB * 64 + ((pr * 8) ^ ((colB & 7) << 3))]) = bv;
            }
        }
        __syncthreads();
        #pragma unroll
        for (int ks = 0; ks < 2; ++ks) {
            s8v a[FM], b[FN];
            #pragma unroll
            for (int m_ = 0; m_ < FM; ++m_) {
                int row = wr * WM + m_ * 16 + l15;
                a[m_] = *(const s8v*)(&As[row * 64 + ((ks * 32 + l4 * 8) ^ ((row & 7) << 3))]);
            }
            #pragma unroll
            for (int n_ = 0; n_ < FN; ++n_) {
                int col = wc * WN + n_ * 16 + l15;
                b[n_] = *(const s8v*)(&Bs[col * 64 + ((ks * 32 + l4 * 8) ^ ((col & 7) << 3))]);
            }
            #pragma unroll
            for (int m_ = 0; m_ < FM; ++m_)
                #pragma unroll
                for (int n_ = 0; n_ < FN; ++n_)
                    acc[m_][n_] = __builtin_amdgcn_mfma_f32_16x16x32_bf16(
                        a[m_], b[n_], acc[m_][n_], 0, 0, 0);
        }
    }
    if constexpr (MODE == 0) {
        float* Y = (float*)Yv;
        #pragma unroll
        for (int m_ = 0; m_ < FM; ++m_)
            #pragma unroll
            for (int n_ = 0; n_ < FN; ++n_)
                #pragma unroll
                for (int r = 0; r < 4; ++r)
                    Y[(size_t)(br * BM + wr * WM + m_ * 16 + l4 * 4 + r) * OUT
                      + bc * BN + wc * WN + n_ * 16 + l15] = acc[m_][n_][r];
    } else {
        short* Vt = (short*)Yv;   // [OUT][TSEQ] bf16
        #pragma unroll
        for (int m_ = 0; m_ < FM; ++m_)
            #pragma unroll
            for (int n_ = 0; n_ < FN; ++n_) {
                int col  = bc * BN + wc * WN + n_ * 16 + l15;
                int row0 = br * BM + wr * WM + m_ * 16 + l4 * 4;
                s4v pk;
                #pragma unroll
                for (int r = 0; r < 4; ++r) pk[r] = f2bf(acc[m_][n_][r]);
                *(s4v*)(&Vt[(size_t)col * TSEQ + row0]) = pk;
            }
    }
}

// ---------------------------------------------------------------------------
// RoPE (NeoX): reads f32 q,k; writes bf16 Qg (pre-scaled by SCALING*LOG2E)
// and bf16 Kg.
// ---------------------------------------------------------------------------
__global__ __launch_bounds__(256) void rope_bf16(
    const int* __restrict__ pos, const float* __restrict__ qf,
    const float* __restrict__ kf, short* __restrict__ Qg, short* __restrict__ Kg)
{
    const int t = blockIdx.x;
    const int tid = threadIdx.x;
    const int j = tid & 63;
    const int g = tid >> 6;
    const float p = (float)pos[t];
    const float inv = exp2f(-(float)j * (LOG2_ROPE_BASE / 64.0f));
    const float fr = p * inv;
    float s, c;
    sincosf(fr, &s, &c);
    const float QS = SCALING * LOG2E;
    #pragma unroll
    for (int n = 0; n < 4; ++n) {
        int h = g * 4 + n;
        const float* base = qf + (size_t)t * 2048 + h * 128;
        float x1 = base[j], x2 = base[j + 64];
        Qg[(size_t)t * 2048 + h * 128 + j]      = f2bf((x1 * c - x2 * s) * QS);
        Qg[(size_t)t * 2048 + h * 128 + j + 64] = f2bf((x2 * c + x1 * s) * QS);
    }
    {
        int h = g;
        const float* base = kf + (size_t)t * 512 + h * 128;
        float x1 = base[j], x2 = base[j + 64];
        Kg[(size_t)t * 512 + h * 128 + j]      = f2bf(x1 * c - x2 * s);
        Kg[(size_t)t * 512 + h * 128 + j + 64] = f2bf(x2 * c + x1 * s);
    }
}

// ---------------------------------------------------------------------------
// Swapped-operand 32x32 MFMA flash attention, SINGLE-WAVE workgroups.
// One wave = one (head, 32-row q-tile); KVBLK=32; 16 KB LDS per block;
// no barriers (same-wave LDS deps ordered by lgkmcnt). Grid = 1024 blocks,
// heavy tiles first for dynamic load balance.
// mfma(A=K,B=Q) -> S with q=lane&31 (lane-local softmax);
// mfma(A=Vt,B=P^T) -> O^T with q=lane&31 (scalar rescale).
// D layout (32x32): col=lane&31, row=(reg&3)+8*(reg>>2)+4*(lane>>5).
// ---------------------------------------------------------------------------
__global__ __launch_bounds__(64, 3) void attn32w(
    const short* __restrict__ Qg, const short* __restrict__ Kg,
    const short* __restrict__ Vtg, short* __restrict__ out)
{
    __shared__ __align__(16) short Ks[32 * 128];   // [krow][d], 16B-unit swizzled
    __shared__ __align__(16) short Vs[128 * 32];   // [d][krow], 16B-unit swizzled

    const int l = threadIdx.x;            // 0..63
    const int h = l >> 5, q = l & 31;
    const int bid = blockIdx.x;
    const int jt = 63 - (bid >> 4);       // heavy q-tiles first
    const int head = bid & 15;
    const int kvh = head >> 2;
    const int q0 = jt * 32;

    // persistent Q fragments (B-operand): col=q, k=(lane>>5)*8+j over d
    s8v qf[8];
    {
        const short* qp = Qg + (size_t)(q0 + q) * 2048 + head * 128 + h * 8;
        #pragma unroll
        for (int d8 = 0; d8 < 8; ++d8) qf[d8] = *(const s8v*)(qp + d8 * 16);
    }

    f16v O[4];
    #pragma unroll
    for (int dt = 0; dt < 4; ++dt)
        #pragma unroll
        for (int r = 0; r < 16; ++r) O[dt][r] = 0.0f;
    float m = -1e30f, lsum = 0.0f;

    const int nch = jt + 1;
    for (int kc = 0; kc < nch; ++kc) {
        const int k0 = kc * 32;
        // --- stage K chunk [32][128] bf16 (coalesced, row-XOR swizzle) ---
        #pragma unroll
        for (int n = 0; n < 8; ++n) {
            int f = l + 64 * n;
            int r = f >> 4, u = f & 15;
            s8v kv_ = *(const s8v*)(Kg + (size_t)(k0 + r) * 512 + kvh * 128 + u * 8);
            *(s8v*)(&Ks[(r * 16 + (u ^ (r & 15))) * 8]) = kv_;
        }
        // --- stage Vt chunk [128][32] bf16 ---
        #pragma unroll
        for (int n = 0; n < 8; ++n) {
            int f = l + 64 * n;
            int d = f >> 2, u = f & 3;
            s8v vv = *(const s8v*)(Vtg + (size_t)(kvh * 128 + d) * TSEQ + k0 + u * 8);
            *(s8v*)(&Vs[(d * 4 + (u ^ (d & 3))) * 8]) = vv;
        }

        // --- QK^T swapped: pD[reg] = S[krow(reg,h)][q] ---
        f16v pD;
        #pragma unroll
        for (int r = 0; r < 16; ++r) pD[r] = 0.0f;
        #pragma unroll
        for (int d8 = 0; d8 < 8; ++d8) {
            s8v kf = *(const s8v*)(&Ks[(q * 16 + ((d8 * 2 + h) ^ (q & 15))) * 8]);
            pD = __builtin_amdgcn_mfma_f32_32x32x16_bf16(kf, qf[d8], pD, 0, 0, 0);
        }
        // --- causal mask (last chunk only; positions are arange) ---
        if (kc == nch - 1) {
            #pragma unroll
            for (int r = 0; r < 16; ++r) {
                int koff = (r & 3) + 8 * (r >> 2) + 4 * h;
                if (k0 + koff > q0 + q) pD[r] = -1e30f;
            }
        }
        // --- row max: lane-local tree + one cross-half shfl ---
        float mx = pD[0];
        #pragma unroll
        for (int r = 1; r < 16; ++r) mx = fmaxf(mx, pD[r]);
        mx = fmaxf(mx, __shfl_xor(mx, 32, 64));
        const float mn = fmaxf(m, mx);
        const float sc = exp2f(m - mn);   // S already in log2 domain (Q pre-scaled)
        // --- P = exp2(S - m), row sum ---
        float rs = 0.0f;
        #pragma unroll
        for (int r = 0; r < 16; ++r) {
            float pv = exp2f(pD[r] - mn);
            pD[r] = pv;
            rs += pv;
        }
        rs += __shfl_xor(rs, 32, 64);
        lsum = lsum * sc + rs;
        m = mn;
        // --- rescale O (scalar per lane) ---
        #pragma unroll
        for (int dt = 0; dt < 4; ++dt)
            #pragma unroll
            for (int r = 0; r < 16; ++r) O[dt][r] *= sc;
        // --- pack P -> bf16 B-fragments (exchange quads with lane^32) ---
        s8v pf[2];
        #pragma unroll
        for (int s = 0; s < 2; ++s) {
            const int bk = 8 * s + 4 * h;        // own (keep) quad
            const int bs = 8 * s + 4 * (1 - h);  // send quad
            unsigned kp0 = pk2(pD[bk + 0], pD[bk + 1]);
            unsigned kp1 = pk2(pD[bk + 2], pD[bk + 3]);
            unsigned sp0 = pk2(pD[bs + 0], pD[bs + 1]);
            unsigned sp1 = pk2(pD[bs + 2], pD[bs + 3]);
            unsigned r0 = __shfl_xor((int)sp0, 32, 64);
            unsigned r1 = __shfl_xor((int)sp1, 32, 64);
            union { unsigned u[4]; s8v v; } fr;
            fr.u[0] = h ? r0 : kp0;
            fr.u[1] = h ? r1 : kp1;
            fr.u[2] = h ? kp0 : r0;
            fr.u[3] = h ? kp1 : r1;
            pf[s] = fr.v;
        }
        // --- PV swapped: O^T[dt] += Vt-frag * P^T-frag ---
        #pragma unroll
        for (int s = 0; s < 2; ++s) {
            #pragma unroll
            for (int dt = 0; dt < 4; ++dt) {
                int r = dt * 32 + q;
                s8v vf = *(const s8v*)(&Vs[(r * 4 + ((2 * s + h) ^ (r & 3))) * 8]);
                O[dt] = __builtin_amdgcn_mfma_f32_32x32x16_bf16(vf, pf[s], O[dt], 0, 0, 0);
            }
        }
    }

    // --- epilogue: out[q][head*128 + d] = O/l (bf16) ---
    const float il = 1.0f / lsum;
    #pragma unroll
    for (int dt = 0; dt < 4; ++dt)
        #pragma unroll
        for (int g2 = 0; g2 < 4; ++g2) {
            int d4 = dt * 32 + 8 * g2 + 4 * h;
            s4v ov;
            #pragma unroll
            for (int r = 0; r < 4; ++r) ov[r] = f2bf(O[dt][g2 * 4 + r] * il);
            *(s4v*)(out + (size_t)(q0 + q) * 2048 + head * 128 + d4) = ov;
        }
}

// ---------------------------------------------------------------------------
extern "C" void kernel_launch(void* const* d_in, const int* in_sizes, int n_in,
                              void* d_out, int out_size, void* d_ws, size_t ws_size,
                              hipStream_t stream)
{
    const int*   positions = (const int*)  d_in[0];
    const float* hidden    = (const float*)d_in[1];
    const int*   q_qw = (const int*)  d_in[2];
    const float* q_sc = (const float*)d_in[3];
    const int*   q_zr = (const int*)  d_in[4];
    const int*   k_qw = (const int*)  d_in[5];
    const float* k_sc = (const float*)d_in[6];
    const int*   k_zr = (const int*)  d_in[7];
    const int*   v_qw = (const int*)  d_in[8];
    const float* v_sc = (const float*)d_in[9];
    const int*   v_zr = (const int*)  d_in[10];
    const int*   o_qw = (const int*)  d_in[11];
    const float* o_sc = (const float*)d_in[12];
    const int*   o_zr = (const int*)  d_in[13];
    float* outf = (float*)d_out;

    // workspace (32 MB), lifetime-based aliasing:
    //  [0,16M):  qbuf f32[T,2048]   -> later abuf bf16[T,2048] (attn out)
    //  [16M,20M): kbuf f32[T,512]
    //  [20M,28M): hb bf16[2048,2048] -> later Qg bf16[T,2048] (rope out)
    //  [28M,30M): Kg bf16[T,512]
    //  [30M,32M): Vtg bf16[512,T]
    char* base = (char*)d_ws;
    float* qbuf = (float*)(base);
    short* abuf = (short*)(base);
    float* kbuf = (float*)(base + (16u << 20));
    short* hb   = (short*)(base + (20u << 20));
    short* Qg   = (short*)(base + (20u << 20));
    short* Kg   = (short*)(base + (28u << 20));
    short* Vtg  = (short*)(base + (30u << 20));

    dim3 blk(256);
    f32_to_bf16<<<dim3(2048), blk, 0, stream>>>(hidden, hb);
    gemm_gptq_mfma<128, 64, 0><<<dim3(32, 16), blk, 0, stream>>>(hb, q_qw, q_sc, q_zr, qbuf, 2048);
    gemm_gptq_mfma<64, 64, 0><<<dim3(8, 32), blk, 0, stream>>>(hb, k_qw, k_sc, k_zr, kbuf, 512);
    gemm_gptq_mfma<64, 64, 1><<<dim3(8, 32), blk, 0, stream>>>(hb, v_qw, v_sc, v_zr, (void*)Vtg, 512);
    rope_bf16<<<dim3(TSEQ), blk, 0, stream>>>(positions, qbuf, kbuf, Qg, Kg);
    attn32w<<<dim3(1024), dim3(64), 0, stream>>>(Qg, Kg, Vtg, abuf);
    gemm_gptq_mfma<128, 64, 0><<<dim3(32, 16), blk, 0, stream>>>(abuf, o_qw, o_sc, o_zr, outf, 2048);
}

// Round 6
// 293.539 us; speedup vs baseline: 1.9256x; 1.9256x over previous
//
#include <hip/hip_runtime.h>
#include <hip/hip_bf16.h>
#include <math.h>

// Problem constants (Qwen2MoeAttention, T=2048)
#define TSEQ   2048
#define HID    2048
#define NH     16
#define NKV    4
#define HD     128
#define KVD    512
#define SCALING 0.08838834764831845f   // 1/sqrt(128)
#define LOG2_ROPE_BASE 19.931568569324174f  // log2(1e6)
#define LOG2E  1.4426950408889634f

typedef float f4  __attribute__((ext_vector_type(4),  aligned(16)));
typedef float f16v __attribute__((ext_vector_type(16), aligned(64)));
typedef short s8v __attribute__((ext_vector_type(8),  aligned(16)));
typedef short s4v __attribute__((ext_vector_type(4),  aligned(8)));

__device__ __forceinline__ short f2bf(float x) {
    union { __hip_bfloat16 b; short s; } u;
    u.b = __float2bfloat16(x);
    return u.s;
}
__device__ __forceinline__ float bf2f(short s) {
    union { unsigned u; float f; } v;
    v.u = ((unsigned)(unsigned short)s) << 16;
    return v.f;
}
__device__ __forceinline__ unsigned pk2(float a, float b) {
    return ((unsigned)(unsigned short)f2bf(b) << 16) | (unsigned)(unsigned short)f2bf(a);
}

// ---------------------------------------------------------------------------
// f32 -> bf16 bulk convert (hidden_states), 8 elems/thread
// ---------------------------------------------------------------------------
__global__ __launch_bounds__(256) void f32_to_bf16(
    const float* __restrict__ in, short* __restrict__ out)
{
    const int i = (blockIdx.x * 256 + threadIdx.x) * 8;
    f4 a = *(const f4*)(in + i);
    f4 b = *(const f4*)(in + i + 4);
    s8v v;
    v[0] = f2bf(a[0]); v[1] = f2bf(a[1]); v[2] = f2bf(a[2]); v[3] = f2bf(a[3]);
    v[4] = f2bf(b[0]); v[5] = f2bf(b[1]); v[6] = f2bf(b[2]); v[7] = f2bf(b[3]);
    *(s8v*)(out + i) = v;
}

// ---------------------------------------------------------------------------
// MFMA GPTQ GEMM (16x16x32). MODE 0: f32 row-major out. MODE 1: bf16
// transposed out (Vt[col][T] for attention's V^T operand).
// ---------------------------------------------------------------------------
template<int BM, int BN, int MODE>
__global__ __launch_bounds__(256) void gemm_gptq_mfma(
    const short* __restrict__ X, const int* __restrict__ qw,
    const float* __restrict__ scales, const int* __restrict__ zeros,
    void* __restrict__ Yv, int OUT)
{
    constexpr int WM = BM / 2, WN = BN / 2, FM = WM / 16, FN = WN / 16;
    __shared__ __align__(16) short As[BM * 64];
    __shared__ __align__(16) short Bs[BN * 64];
    const int tid = threadIdx.x;
    const int l = tid & 63, w = tid >> 6;
    const int l15 = l & 15, l4 = l >> 4;
    const int wr = w >> 1, wc = w & 1;
    const int br = blockIdx.y, bc = blockIdx.x;

    const int colB = tid % BN;
    const int colg = bc * BN + colB;
    const int prb  = (tid / BN) * (BN / 32);

    f4 acc[FM][FN] = {};

    for (int kt = 0; kt < 32; ++kt) {
        __syncthreads();
        #pragma unroll
        for (int n = 0; n < BM / 32; ++n) {
            int f = tid + 256 * n;
            int r = f >> 3, c8 = f & 7;
            s8v av = *(const s8v*)(X + (size_t)(br * BM + r) * 2048 + kt * 64 + c8 * 8);
            *(s8v*)(&As[r * 64 + ((c8 * 8) ^ ((r & 7) << 3))]) = av;
        }
        {
            const int g = kt >> 1;
            const float sc = scales[g * OUT + colg];
            const float zf = (float)zeros[g * OUT + colg];
            #pragma unroll
            for (int n = 0; n < BN / 32; ++n) {
                int pr = prb + n;
                unsigned p = (unsigned)qw[(kt * 8 + pr) * OUT + colg];
                s8v bv;
                #pragma unroll
                for (int s = 0; s < 8; ++s) {
                    float qv = (float)((p >> (4 * s)) & 15u);
                    bv[s] = f2bf((qv - zf) * sc);
                }
                *(s8v*)(&Bs[colB * 64 + ((pr * 8) ^ ((colB & 7) << 3))]) = bv;
            }
        }
        __syncthreads();
        #pragma unroll
        for (int ks = 0; ks < 2; ++ks) {
            s8v a[FM], b[FN];
            #pragma unroll
            for (int m_ = 0; m_ < FM; ++m_) {
                int row = wr * WM + m_ * 16 + l15;
                a[m_] = *(const s8v*)(&As[row * 64 + ((ks * 32 + l4 * 8) ^ ((row & 7) << 3))]);
            }
            #pragma unroll
            for (int n_ = 0; n_ < FN; ++n_) {
                int col = wc * WN + n_ * 16 + l15;
                b[n_] = *(const s8v*)(&Bs[col * 64 + ((ks * 32 + l4 * 8) ^ ((col & 7) << 3))]);
            }
            #pragma unroll
            for (int m_ = 0; m_ < FM; ++m_)
                #pragma unroll
                for (int n_ = 0; n_ < FN; ++n_)
                    acc[m_][n_] = __builtin_amdgcn_mfma_f32_16x16x32_bf16(
                        a[m_], b[n_], acc[m_][n_], 0, 0, 0);
        }
    }
    if constexpr (MODE == 0) {
        float* Y = (float*)Yv;
        #pragma unroll
        for (int m_ = 0; m_ < FM; ++m_)
            #pragma unroll
            for (int n_ = 0; n_ < FN; ++n_)
                #pragma unroll
                for (int r = 0; r < 4; ++r)
                    Y[(size_t)(br * BM + wr * WM + m_ * 16 + l4 * 4 + r) * OUT
                      + bc * BN + wc * WN + n_ * 16 + l15] = acc[m_][n_][r];
    } else {
        short* Vt = (short*)Yv;   // [OUT][TSEQ] bf16
        #pragma unroll
        for (int m_ = 0; m_ < FM; ++m_)
            #pragma unroll
            for (int n_ = 0; n_ < FN; ++n_) {
                int col  = bc * BN + wc * WN + n_ * 16 + l15;
                int row0 = br * BM + wr * WM + m_ * 16 + l4 * 4;
                s4v pk;
                #pragma unroll
                for (int r = 0; r < 4; ++r) pk[r] = f2bf(acc[m_][n_][r]);
                *(s4v*)(&Vt[(size_t)col * TSEQ + row0]) = pk;
            }
    }
}

// ---------------------------------------------------------------------------
// RoPE (NeoX): reads f32 q,k; writes bf16 Qg (pre-scaled by SCALING*LOG2E)
// and bf16 Kg.
// ---------------------------------------------------------------------------
__global__ __launch_bounds__(256) void rope_bf16(
    const int* __restrict__ pos, const float* __restrict__ qf,
    const float* __restrict__ kf, short* __restrict__ Qg, short* __restrict__ Kg)
{
    const int t = blockIdx.x;
    const int tid = threadIdx.x;
    const int j = tid & 63;
    const int g = tid >> 6;
    const float p = (float)pos[t];
    const float inv = exp2f(-(float)j * (LOG2_ROPE_BASE / 64.0f));
    const float fr = p * inv;
    float s, c;
    sincosf(fr, &s, &c);
    const float QS = SCALING * LOG2E;
    #pragma unroll
    for (int n = 0; n < 4; ++n) {
        int h = g * 4 + n;
        const float* base = qf + (size_t)t * 2048 + h * 128;
        float x1 = base[j], x2 = base[j + 64];
        Qg[(size_t)t * 2048 + h * 128 + j]      = f2bf((x1 * c - x2 * s) * QS);
        Qg[(size_t)t * 2048 + h * 128 + j + 64] = f2bf((x2 * c + x1 * s) * QS);
    }
    {
        int h = g;
        const float* base = kf + (size_t)t * 512 + h * 128;
        float x1 = base[j], x2 = base[j + 64];
        Kg[(size_t)t * 512 + h * 128 + j]      = f2bf(x1 * c - x2 * s);
        Kg[(size_t)t * 512 + h * 128 + j + 64] = f2bf(x2 * c + x1 * s);
    }
}

// ---------------------------------------------------------------------------
// Swapped-operand 32x32 MFMA flash attention with K-SPLIT=2 (flash-decoding
// style) and T14 async staging (issue next chunk's loads before computing
// the current one). Block = 4 waves = 4 q-heads of a GQA group, shared K/Vt
// staging; blockIdx = (qtile, kvh, split). Writes UNNORMALIZED bf16 partial
// O + (m,l) stats; attn_combine merges the two splits.
// D layout (32x32): col=lane&31, row=(reg&3)+8*(reg>>2)+4*(lane>>5).
// ---------------------------------------------------------------------------
__global__ __launch_bounds__(256, 2) void attn32s(
    const short* __restrict__ Qg, const short* __restrict__ Kg,
    const short* __restrict__ Vtg, short* __restrict__ Op0,
    short* __restrict__ Op1, float2* __restrict__ stats)
{
    __shared__ __align__(16) short Ks[64 * 128];   // [krow][d], 16B-unit swizzled
    __shared__ __align__(16) short Vs[128 * 64];   // [d][krow], 16B-unit swizzled

    const int tid = threadIdx.x;
    const int l = tid & 63, w = tid >> 6;
    const int h = l >> 5, q = l & 31;
    const int jt = 63 - blockIdx.x;       // heavy q-tiles first
    const int kvh = blockIdx.y;
    const int z = blockIdx.z;
    const int q0 = jt * 32;
    const int head = kvh * 4 + w;

    const int nchTot = (jt >> 1) + 1;     // total 64-key chunks for this q-tile
    const int h0 = nchTot >> 1;
    const int c0 = z ? h0 : 0;
    const int c1 = z ? nchTot : h0;

    // persistent Q fragments (B-operand): col=q, k=(lane>>5)*8+j over d
    s8v qf[8];
    {
        const short* qp = Qg + (size_t)(q0 + q) * 2048 + head * 128 + h * 8;
        #pragma unroll
        for (int d8 = 0; d8 < 8; ++d8) qf[d8] = *(const s8v*)(qp + d8 * 16);
    }

    f16v O[4];
    #pragma unroll
    for (int dt = 0; dt < 4; ++dt)
        #pragma unroll
        for (int r = 0; r < 16; ++r) O[dt][r] = 0.0f;
    float m = -1e30f, lsum = 0.0f;

    if (c0 < c1) {
        s8v kreg[4], vreg[4];
        // prefetch chunk c0
        {
            const int k0 = c0 * 64;
            #pragma unroll
            for (int n = 0; n < 4; ++n) {
                int f = tid + 256 * n;
                int r = f >> 4, u = f & 15;
                kreg[n] = *(const s8v*)(Kg + (size_t)(k0 + r) * 512 + kvh * 128 + u * 8);
            }
            #pragma unroll
            for (int n = 0; n < 4; ++n) {
                int f = tid + 256 * n;
                int d = f >> 3, u = f & 7;
                vreg[n] = *(const s8v*)(Vtg + (size_t)(kvh * 128 + d) * TSEQ + k0 + u * 8);
            }
        }
        for (int kc = c0; kc < c1; ++kc) {
            const int k0 = kc * 64;
            __syncthreads();   // previous chunk fully consumed -> LDS free
            // --- write staged regs to LDS ---
            #pragma unroll
            for (int n = 0; n < 4; ++n) {
                int f = tid + 256 * n;
                int r = f >> 4, u = f & 15;
                *(s8v*)(&Ks[(r * 16 + (u ^ (r & 7))) * 8]) = kreg[n];
            }
            #pragma unroll
            for (int n = 0; n < 4; ++n) {
                int f = tid + 256 * n;
                int d = f >> 3, u = f & 7;
                *(s8v*)(&Vs[(d * 8 + (u ^ (d & 7))) * 8]) = vreg[n];
            }
            // --- issue next chunk's global loads (latency hides under compute) ---
            if (kc + 1 < c1) {
                const int kn = (kc + 1) * 64;
                #pragma unroll
                for (int n = 0; n < 4; ++n) {
                    int f = tid + 256 * n;
                    int r = f >> 4, u = f & 15;
                    kreg[n] = *(const s8v*)(Kg + (size_t)(kn + r) * 512 + kvh * 128 + u * 8);
                }
                #pragma unroll
                for (int n = 0; n < 4; ++n) {
                    int f = tid + 256 * n;
                    int d = f >> 3, u = f & 7;
                    vreg[n] = *(const s8v*)(Vtg + (size_t)(kvh * 128 + d) * TSEQ + kn + u * 8);
                }
            }
            __syncthreads();   // staged LDS visible

            // --- QK^T swapped: pD[t] = S[k-tile t][q] ---
            f16v pD[2];
            #pragma unroll
            for (int t = 0; t < 2; ++t)
                #pragma unroll
                for (int r = 0; r < 16; ++r) pD[t][r] = 0.0f;
            #pragma unroll
            for (int t = 0; t < 2; ++t) {
                #pragma unroll
                for (int d8 = 0; d8 < 8; ++d8) {
                    int r = t * 32 + q;
                    s8v kf = *(const s8v*)(&Ks[(r * 16 + ((d8 * 2 + h) ^ (r & 7))) * 8]);
                    pD[t] = __builtin_amdgcn_mfma_f32_32x32x16_bf16(kf, qf[d8], pD[t], 0, 0, 0);
                }
            }
            // --- causal mask (global last chunk only; reachable only in z=1) ---
            if (kc == nchTot - 1) {
                #pragma unroll
                for (int t = 0; t < 2; ++t)
                    #pragma unroll
                    for (int r = 0; r < 16; ++r) {
                        int koff = (r & 3) + 8 * (r >> 2) + 4 * h + 32 * t;
                        if (k0 + koff > q0 + q) pD[t][r] = -1e30f;
                    }
            }
            // --- row max: lane-local tree + one cross-half shfl ---
            float mx = pD[0][0];
            #pragma unroll
            for (int r = 1; r < 16; ++r) mx = fmaxf(mx, pD[0][r]);
            #pragma unroll
            for (int r = 0; r < 16; ++r) mx = fmaxf(mx, pD[1][r]);
            mx = fmaxf(mx, __shfl_xor(mx, 32, 64));
            const float mn = fmaxf(m, mx);
            const float sc = exp2f(m - mn);   // log2 domain (Q pre-scaled)
            // --- P = exp2(S - m), row sum ---
            float rs = 0.0f;
            #pragma unroll
            for (int t = 0; t < 2; ++t)
                #pragma unroll
                for (int r = 0; r < 16; ++r) {
                    float pv = exp2f(pD[t][r] - mn);
                    pD[t][r] = pv;
                    rs += pv;
                }
            rs += __shfl_xor(rs, 32, 64);
            lsum = lsum * sc + rs;
            m = mn;
            // --- rescale O (scalar per lane) ---
            #pragma unroll
            for (int dt = 0; dt < 4; ++dt)
                #pragma unroll
                for (int r = 0; r < 16; ++r) O[dt][r] *= sc;
            // --- pack P -> bf16 B-fragments (exchange quads with lane^32) ---
            s8v pf[4];
            #pragma unroll
            for (int s = 0; s < 4; ++s) {
                const int t = s >> 1, c = s & 1;
                const int bk = 8 * c + 4 * h;
                const int bs = 8 * c + 4 * (1 - h);
                unsigned kp0 = pk2(pD[t][bk + 0], pD[t][bk + 1]);
                unsigned kp1 = pk2(pD[t][bk + 2], pD[t][bk + 3]);
                unsigned sp0 = pk2(pD[t][bs + 0], pD[t][bs + 1]);
                unsigned sp1 = pk2(pD[t][bs + 2], pD[t][bs + 3]);
                unsigned r0 = __shfl_xor((int)sp0, 32, 64);
                unsigned r1 = __shfl_xor((int)sp1, 32, 64);
                union { unsigned u[4]; s8v v; } fr;
                fr.u[0] = h ? r0 : kp0;
                fr.u[1] = h ? r1 : kp1;
                fr.u[2] = h ? kp0 : r0;
                fr.u[3] = h ? kp1 : r1;
                pf[s] = fr.v;
            }
            // --- PV swapped: O^T[dt] += Vt-frag * P^T-frag ---
            #pragma unroll
            for (int s = 0; s < 4; ++s) {
                #pragma unroll
                for (int dt = 0; dt < 4; ++dt) {
                    int r = dt * 32 + q;
                    s8v vf = *(const s8v*)(&Vs[(r * 8 + ((2 * s + h) ^ (r & 7))) * 8]);
                    O[dt] = __builtin_amdgcn_mfma_f32_32x32x16_bf16(vf, pf[s], O[dt], 0, 0, 0);
                }
            }
        }
    }

    // --- epilogue: UNNORMALIZED partial O (bf16) + stats ---
    short* Opz = z ? Op1 : Op0;
    #pragma unroll
    for (int dt = 0; dt < 4; ++dt)
        #pragma unroll
        for (int g2 = 0; g2 < 4; ++g2) {
            int d4 = dt * 32 + 8 * g2 + 4 * h;
            s4v ov;
            #pragma unroll
            for (int r = 0; r < 4; ++r) ov[r] = f2bf(O[dt][g2 * 4 + r]);
            *(s4v*)(Opz + (size_t)(q0 + q) * 2048 + head * 128 + d4) = ov;
        }
    if (h == 0)
        stats[((size_t)z * NH + head) * TSEQ + q0 + q] = make_float2(m, lsum);
}

// ---------------------------------------------------------------------------
// Combine the two K-split partials: O = (O0*w0 + O1*w1) / (l0*w0 + l1*w1),
// w_i = exp2(m_i - max(m0,m1)). Block = 16 (row,head) pairs; thread owns 8 d.
// ---------------------------------------------------------------------------
__global__ __launch_bounds__(256) void attn_combine(
    const short* __restrict__ Op0, const short* __restrict__ Op1,
    const float2* __restrict__ stats, short* __restrict__ out)
{
    const int gp = blockIdx.x * 16 + (threadIdx.x >> 4);   // row*16 + head
    const int row = gp >> 4;
    const int head = gp & 15;
    const int d0 = (threadIdx.x & 15) * 8;
    const float2 s0 = stats[(size_t)head * TSEQ + row];
    const float2 s1 = stats[(size_t)(NH + head) * TSEQ + row];
    const float M = fmaxf(s0.x, s1.x);
    const float w0 = exp2f(s0.x - M), w1 = exp2f(s1.x - M);
    const float inv = 1.0f / (s0.y * w0 + s1.y * w1);
    const size_t off = (size_t)row * 2048 + head * 128 + d0;
    s8v a = *(const s8v*)(Op0 + off);
    s8v b = *(const s8v*)(Op1 + off);
    s8v o;
    #pragma unroll
    for (int j = 0; j < 8; ++j)
        o[j] = f2bf((bf2f(a[j]) * w0 + bf2f(b[j]) * w1) * inv);
    *(s8v*)(out + off) = o;
}

// ---------------------------------------------------------------------------
extern "C" void kernel_launch(void* const* d_in, const int* in_sizes, int n_in,
                              void* d_out, int out_size, void* d_ws, size_t ws_size,
                              hipStream_t stream)
{
    const int*   positions = (const int*)  d_in[0];
    const float* hidden    = (const float*)d_in[1];
    const int*   q_qw = (const int*)  d_in[2];
    const float* q_sc = (const float*)d_in[3];
    const int*   q_zr = (const int*)  d_in[4];
    const int*   k_qw = (const int*)  d_in[5];
    const float* k_sc = (const float*)d_in[6];
    const int*   k_zr = (const int*)  d_in[7];
    const int*   v_qw = (const int*)  d_in[8];
    const float* v_sc = (const float*)d_in[9];
    const int*   v_zr = (const int*)  d_in[10];
    const int*   o_qw = (const int*)  d_in[11];
    const float* o_sc = (const float*)d_in[12];
    const int*   o_zr = (const int*)  d_in[13];
    float* outf = (float*)d_out;

    // workspace (40 MB), lifetime-based aliasing:
    //  [0,16M):  qbuf f32[T,2048] (dead after rope)
    //            -> abuf bf16[T,2048] @ [0,8M) (combine out, o-gemm in)
    //            -> Op0 bf16[T,2048] @ [8,16M) (split-0 partial)
    //  [16,20M): kbuf f32[T,512] (dead after rope) -> stats float2[2][NH][T] @ [16,16.5M)
    //  [20,28M): hb bf16[2048,2048] (dead after v-gemm) -> Qg bf16[T,2048] (rope out)
    //  [28,30M): Kg bf16[T,512]
    //  [30,32M): Vtg bf16[512,T]
    //  [32,40M): Op1 bf16[T,2048] (split-1 partial)
    char* base = (char*)d_ws;
    float* qbuf = (float*)(base);
    short* abuf = (short*)(base);
    short* Op0  = (short*)(base + (8u << 20));
    float* kbuf = (float*)(base + (16u << 20));
    float2* stats = (float2*)(base + (16u << 20));
    short* hb   = (short*)(base + (20u << 20));
    short* Qg   = (short*)(base + (20u << 20));
    short* Kg   = (short*)(base + (28u << 20));
    short* Vtg  = (short*)(base + (30u << 20));
    short* Op1  = (short*)(base + (32u << 20));

    dim3 blk(256);
    f32_to_bf16<<<dim3(2048), blk, 0, stream>>>(hidden, hb);
    gemm_gptq_mfma<128, 64, 0><<<dim3(32, 16), blk, 0, stream>>>(hb, q_qw, q_sc, q_zr, qbuf, 2048);
    gemm_gptq_mfma<64, 64, 0><<<dim3(8, 32), blk, 0, stream>>>(hb, k_qw, k_sc, k_zr, kbuf, 512);
    gemm_gptq_mfma<64, 64, 1><<<dim3(8, 32), blk, 0, stream>>>(hb, v_qw, v_sc, v_zr, (void*)Vtg, 512);
    rope_bf16<<<dim3(TSEQ), blk, 0, stream>>>(positions, qbuf, kbuf, Qg, Kg);
    attn32s<<<dim3(64, 4, 2), blk, 0, stream>>>(Qg, Kg, Vtg, Op0, Op1, stats);
    attn_combine<<<dim3(TSEQ * NH / 16), blk, 0, stream>>>(Op0, Op1, stats, abuf);
    gemm_gptq_mfma<128, 64, 0><<<dim3(32, 16), blk, 0, stream>>>(abuf, o_qw, o_sc, o_zr, outf, 2048);
}

// Round 7
// 242.240 us; speedup vs baseline: 2.3334x; 1.2118x over previous
//
#include <hip/hip_runtime.h>
#include <hip/hip_bf16.h>
#include <math.h>

// Problem constants (Qwen2MoeAttention, T=2048)
#define TSEQ   2048
#define HID    2048
#define NH     16
#define NKV    4
#define HD     128
#define KVD    512
#define SCALING 0.08838834764831845f   // 1/sqrt(128)
#define LOG2_ROPE_BASE 19.931568569324174f  // log2(1e6)
#define LOG2E  1.4426950408889634f

typedef float f4  __attribute__((ext_vector_type(4),  aligned(16)));
typedef float f16v __attribute__((ext_vector_type(16), aligned(64)));
typedef short s8v __attribute__((ext_vector_type(8),  aligned(16)));
typedef short s4v __attribute__((ext_vector_type(4),  aligned(8)));

__device__ __forceinline__ short f2bf(float x) {
    union { __hip_bfloat16 b; short s; } u;
    u.b = __float2bfloat16(x);
    return u.s;
}
__device__ __forceinline__ float bf2f(short s) {
    union { unsigned u; float f; } v;
    v.u = ((unsigned)(unsigned short)s) << 16;
    return v.f;
}
__device__ __forceinline__ unsigned pk2(float a, float b) {
    return ((unsigned)(unsigned short)f2bf(b) << 16) | (unsigned)(unsigned short)f2bf(a);
}
__device__ __forceinline__ void gl_lds16(const void* g, void* l) {
    __builtin_amdgcn_global_load_lds(
        (const __attribute__((address_space(1))) void*)g,
        (__attribute__((address_space(3))) void*)l, 16, 0, 0);
}

// ---------------------------------------------------------------------------
// f32 -> bf16 bulk convert (hidden_states), 8 elems/thread
// ---------------------------------------------------------------------------
__global__ __launch_bounds__(256) void f32_to_bf16(
    const float* __restrict__ in, short* __restrict__ out)
{
    const int i = (blockIdx.x * 256 + threadIdx.x) * 8;
    f4 a = *(const f4*)(in + i);
    f4 b = *(const f4*)(in + i + 4);
    s8v v;
    v[0] = f2bf(a[0]); v[1] = f2bf(a[1]); v[2] = f2bf(a[2]); v[3] = f2bf(a[3]);
    v[4] = f2bf(b[0]); v[5] = f2bf(b[1]); v[6] = f2bf(b[2]); v[7] = f2bf(b[3]);
    *(s8v*)(out + i) = v;
}

// ---------------------------------------------------------------------------
// MFMA GPTQ GEMM (16x16x32). MODE 0: f32 row-major out. MODE 1: bf16
// transposed out (Vt[col][T] for attention's V^T operand).
// ---------------------------------------------------------------------------
template<int BM, int BN, int MODE>
__global__ __launch_bounds__(256) void gemm_gptq_mfma(
    const short* __restrict__ X, const int* __restrict__ qw,
    const float* __restrict__ scales, const int* __restrict__ zeros,
    void* __restrict__ Yv, int OUT)
{
    constexpr int WM = BM / 2, WN = BN / 2, FM = WM / 16, FN = WN / 16;
    __shared__ __align__(16) short As[BM * 64];
    __shared__ __align__(16) short Bs[BN * 64];
    const int tid = threadIdx.x;
    const int l = tid & 63, w = tid >> 6;
    const int l15 = l & 15, l4 = l >> 4;
    const int wr = w >> 1, wc = w & 1;
    const int br = blockIdx.y, bc = blockIdx.x;

    const int colB = tid % BN;
    const int colg = bc * BN + colB;
    const int prb  = (tid / BN) * (BN / 32);

    f4 acc[FM][FN] = {};

    for (int kt = 0; kt < 32; ++kt) {
        __syncthreads();
        #pragma unroll
        for (int n = 0; n < BM / 32; ++n) {
            int f = tid + 256 * n;
            int r = f >> 3, c8 = f & 7;
            s8v av = *(const s8v*)(X + (size_t)(br * BM + r) * 2048 + kt * 64 + c8 * 8);
            *(s8v*)(&As[r * 64 + ((c8 * 8) ^ ((r & 7) << 3))]) = av;
        }
        {
            const int g = kt >> 1;
            const float sc = scales[g * OUT + colg];
            const float zf = (float)zeros[g * OUT + colg];
            #pragma unroll
            for (int n = 0; n < BN / 32; ++n) {
                int pr = prb + n;
                unsigned p = (unsigned)qw[(kt * 8 + pr) * OUT + colg];
                s8v bv;
                #pragma unroll
                for (int s = 0; s < 8; ++s) {
                    float qv = (float)((p >> (4 * s)) & 15u);
                    bv[s] = f2bf((qv - zf) * sc);
                }
                *(s8v*)(&Bs[colB * 64 + ((pr * 8) ^ ((colB & 7) << 3))]) = bv;
            }
        }
        __syncthreads();
        #pragma unroll
        for (int ks = 0; ks < 2; ++ks) {
            s8v a[FM], b[FN];
            #pragma unroll
            for (int m_ = 0; m_ < FM; ++m_) {
                int row = wr * WM + m_ * 16 + l15;
                a[m_] = *(const s8v*)(&As[row * 64 + ((ks * 32 + l4 * 8) ^ ((row & 7) << 3))]);
            }
            #pragma unroll
            for (int n_ = 0; n_ < FN; ++n_) {
                int col = wc * WN + n_ * 16 + l15;
                b[n_] = *(const s8v*)(&Bs[col * 64 + ((ks * 32 + l4 * 8) ^ ((col & 7) << 3))]);
            }
            #pragma unroll
            for (int m_ = 0; m_ < FM; ++m_)
                #pragma unroll
                for (int n_ = 0; n_ < FN; ++n_)
                    acc[m_][n_] = __builtin_amdgcn_mfma_f32_16x16x32_bf16(
                        a[m_], b[n_], acc[m_][n_], 0, 0, 0);
        }
    }
    if constexpr (MODE == 0) {
        float* Y = (float*)Yv;
        #pragma unroll
        for (int m_ = 0; m_ < FM; ++m_)
            #pragma unroll
            for (int n_ = 0; n_ < FN; ++n_)
                #pragma unroll
                for (int r = 0; r < 4; ++r)
                    Y[(size_t)(br * BM + wr * WM + m_ * 16 + l4 * 4 + r) * OUT
                      + bc * BN + wc * WN + n_ * 16 + l15] = acc[m_][n_][r];
    } else {
        short* Vt = (short*)Yv;   // [OUT][TSEQ] bf16
        #pragma unroll
        for (int m_ = 0; m_ < FM; ++m_)
            #pragma unroll
            for (int n_ = 0; n_ < FN; ++n_) {
                int col  = bc * BN + wc * WN + n_ * 16 + l15;
                int row0 = br * BM + wr * WM + m_ * 16 + l4 * 4;
                s4v pk;
                #pragma unroll
                for (int r = 0; r < 4; ++r) pk[r] = f2bf(acc[m_][n_][r]);
                *(s4v*)(&Vt[(size_t)col * TSEQ + row0]) = pk;
            }
    }
}

// ---------------------------------------------------------------------------
// RoPE (NeoX): reads f32 q,k; writes bf16 Qg (pre-scaled by SCALING*LOG2E)
// and bf16 Kg.
// ---------------------------------------------------------------------------
__global__ __launch_bounds__(256) void rope_bf16(
    const int* __restrict__ pos, const float* __restrict__ qf,
    const float* __restrict__ kf, short* __restrict__ Qg, short* __restrict__ Kg)
{
    const int t = blockIdx.x;
    const int tid = threadIdx.x;
    const int j = tid & 63;
    const int g = tid >> 6;
    const float p = (float)pos[t];
    const float inv = exp2f(-(float)j * (LOG2_ROPE_BASE / 64.0f));
    const float fr = p * inv;
    float s, c;
    sincosf(fr, &s, &c);
    const float QS = SCALING * LOG2E;
    #pragma unroll
    for (int n = 0; n < 4; ++n) {
        int h = g * 4 + n;
        const float* base = qf + (size_t)t * 2048 + h * 128;
        float x1 = base[j], x2 = base[j + 64];
        Qg[(size_t)t * 2048 + h * 128 + j]      = f2bf((x1 * c - x2 * s) * QS);
        Qg[(size_t)t * 2048 + h * 128 + j + 64] = f2bf((x2 * c + x1 * s) * QS);
    }
    {
        int h = g;
        const float* base = kf + (size_t)t * 512 + h * 128;
        float x1 = base[j], x2 = base[j + 64];
        Kg[(size_t)t * 512 + h * 128 + j]      = f2bf(x1 * c - x2 * s);
        Kg[(size_t)t * 512 + h * 128 + j + 64] = f2bf(x2 * c + x1 * s);
    }
}

// ---------------------------------------------------------------------------
// Swapped-operand 32x32 MFMA flash attention, K-SPLIT=2, with
// global_load_lds double-buffered staging (pre-swizzled global source,
// linear LDS dest — rule 21) and T13 defer-max (THR=8 in log2 domain).
// Block = 4 waves = 4 q-heads of a GQA group; one barrier per chunk:
//   barrier -> STAGE(next chunk, buf^1) -> compute(buf).
// LDS logical layouts: Ks[r][u16] unit u at slot u^(r&15) (r=0..63, 16
// 16B-units/row); Vs[d][u16] unit u at slot u^(d&7) (d=0..127, 8 units/row).
// D layout (32x32): col=lane&31, row=(reg&3)+8*(reg>>2)+4*(lane>>5).
// ---------------------------------------------------------------------------
__global__ __launch_bounds__(256, 2) void attn32s(
    const short* __restrict__ Qg, const short* __restrict__ Kg,
    const short* __restrict__ Vtg, short* __restrict__ Op0,
    short* __restrict__ Op1, float2* __restrict__ stats)
{
    __shared__ __align__(16) short Ks[2][64 * 128];   // 2 x 16KB
    __shared__ __align__(16) short Vs[2][128 * 64];   // 2 x 16KB

    const int tid = threadIdx.x;
    const int l = tid & 63, w = tid >> 6;
    const int h = l >> 5, q = l & 31;
    const int jt = 63 - blockIdx.x;       // heavy q-tiles first
    const int kvh = blockIdx.y;
    const int z = blockIdx.z;
    const int q0 = jt * 32;
    const int head = kvh * 4 + w;

    const int nchTot = (jt >> 1) + 1;     // total 64-key chunks for this q-tile
    const int h0 = nchTot >> 1;
    const int c0 = z ? h0 : 0;
    const int c1 = z ? nchTot : h0;

    // persistent Q fragments (B-operand): col=q, k=(lane>>5)*8+j over d
    s8v qf[8];
    {
        const short* qp = Qg + (size_t)(q0 + q) * 2048 + head * 128 + h * 8;
        #pragma unroll
        for (int d8 = 0; d8 < 8; ++d8) qf[d8] = *(const s8v*)(qp + d8 * 16);
    }

    f16v O[4];
    #pragma unroll
    for (int dt = 0; dt < 4; ++dt)
        #pragma unroll
        for (int r = 0; r < 16; ++r) O[dt][r] = 0.0f;
    float m = -1e30f, lsum = 0.0f;

    if (c0 < c1) {
        // ---- async stage of one 64-key chunk into buffer `b` ----
        // wave w stages K 16B-units s=w*256..w*256+255 and V units likewise
        // (4 segments of 64 units each); global source pre-swizzled so the
        // linear LDS write realizes the XOR layout.
        auto STAGE = [&](int b, int kc) {
            const int k0s = kc * 64;
            #pragma unroll
            for (int n4 = 0; n4 < 4; ++n4) {
                int n = w * 4 + n4;          // segment 0..15
                int s = n * 64 + l;          // K unit index
                int r = s >> 4, up = s & 15;
                int u = up ^ (r & 15);
                gl_lds16(Kg + (size_t)(k0s + r) * 512 + kvh * 128 + u * 8,
                         &Ks[b][n * 512]);
            }
            #pragma unroll
            for (int n4 = 0; n4 < 4; ++n4) {
                int n = w * 4 + n4;
                int s = n * 64 + l;          // V unit index
                int d = s >> 3, up = s & 7;
                int u = up ^ (d & 7);
                gl_lds16(Vtg + (size_t)(kvh * 128 + d) * TSEQ + k0s + u * 8,
                         &Vs[b][n * 512]);
            }
        };

        STAGE(0, c0);
        int cur = 0;
        for (int kc = c0; kc < c1; ++kc) {
            const int k0 = kc * 64;
            __syncthreads();   // drains vmcnt (staged data in LDS) + lgkmcnt
            if (kc + 1 < c1) STAGE(cur ^ 1, kc + 1);

            // --- QK^T swapped: pD[t] = S[k-tile t][q] ---
            f16v pD[2];
            #pragma unroll
            for (int t = 0; t < 2; ++t)
                #pragma unroll
                for (int r = 0; r < 16; ++r) pD[t][r] = 0.0f;
            #pragma unroll
            for (int t = 0; t < 2; ++t) {
                #pragma unroll
                for (int d8 = 0; d8 < 8; ++d8) {
                    int r = t * 32 + q;
                    s8v kf = *(const s8v*)(
                        &Ks[cur][(r * 16 + ((d8 * 2 + h) ^ (r & 15))) * 8]);
                    pD[t] = __builtin_amdgcn_mfma_f32_32x32x16_bf16(kf, qf[d8], pD[t], 0, 0, 0);
                }
            }
            // --- causal mask (global last chunk; reachable only in z=1) ---
            if (kc == nchTot - 1) {
                #pragma unroll
                for (int t = 0; t < 2; ++t)
                    #pragma unroll
                    for (int r = 0; r < 16; ++r) {
                        int koff = (r & 3) + 8 * (r >> 2) + 4 * h + 32 * t;
                        if (k0 + koff > q0 + q) pD[t][r] = -1e30f;
                    }
            }
            // --- row max: lane-local tree + one cross-half shfl ---
            float mx = pD[0][0];
            #pragma unroll
            for (int r = 1; r < 16; ++r) mx = fmaxf(mx, pD[0][r]);
            #pragma unroll
            for (int r = 0; r < 16; ++r) mx = fmaxf(mx, pD[1][r]);
            mx = fmaxf(mx, __shfl_xor(mx, 32, 64));
            // --- T13 defer-max: only rescale when max grew by >8 (log2) ---
            if (__any(mx - m > 8.0f)) {
                const float mn = fmaxf(m, mx);
                const float sc = exp2f(m - mn);
                #pragma unroll
                for (int dt = 0; dt < 4; ++dt)
                    #pragma unroll
                    for (int r = 0; r < 16; ++r) O[dt][r] *= sc;
                lsum *= sc;
                m = mn;
            }
            // --- P = exp2(S - m) (bounded by 2^8), row sum ---
            float rs = 0.0f;
            #pragma unroll
            for (int t = 0; t < 2; ++t)
                #pragma unroll
                for (int r = 0; r < 16; ++r) {
                    float pv = exp2f(pD[t][r] - m);
                    pD[t][r] = pv;
                    rs += pv;
                }
            rs += __shfl_xor(rs, 32, 64);
            lsum += rs;
            // --- pack P -> bf16 B-fragments (exchange quads with lane^32) ---
            s8v pf[4];
            #pragma unroll
            for (int s = 0; s < 4; ++s) {
                const int t = s >> 1, c = s & 1;
                const int bk = 8 * c + 4 * h;
                const int bs = 8 * c + 4 * (1 - h);
                unsigned kp0 = pk2(pD[t][bk + 0], pD[t][bk + 1]);
                unsigned kp1 = pk2(pD[t][bk + 2], pD[t][bk + 3]);
                unsigned sp0 = pk2(pD[t][bs + 0], pD[t][bs + 1]);
                unsigned sp1 = pk2(pD[t][bs + 2], pD[t][bs + 3]);
                unsigned r0 = __shfl_xor((int)sp0, 32, 64);
                unsigned r1 = __shfl_xor((int)sp1, 32, 64);
                union { unsigned u[4]; s8v v; } fr;
                fr.u[0] = h ? r0 : kp0;
                fr.u[1] = h ? r1 : kp1;
                fr.u[2] = h ? kp0 : r0;
                fr.u[3] = h ? kp1 : r1;
                pf[s] = fr.v;
            }
            // --- PV swapped: O^T[dt] += Vt-frag * P^T-frag ---
            #pragma unroll
            for (int s = 0; s < 4; ++s) {
                #pragma unroll
                for (int dt = 0; dt < 4; ++dt) {
                    int rv = dt * 32 + q;
                    s8v vf = *(const s8v*)(
                        &Vs[cur][(rv * 8 + ((2 * s + h) ^ (rv & 7))) * 8]);
                    O[dt] = __builtin_amdgcn_mfma_f32_32x32x16_bf16(vf, pf[s], O[dt], 0, 0, 0);
                }
            }
            cur ^= 1;
        }
    }

    // --- epilogue: UNNORMALIZED partial O (bf16) + stats ---
    short* Opz = z ? Op1 : Op0;
    #pragma unroll
    for (int dt = 0; dt < 4; ++dt)
        #pragma unroll
        for (int g2 = 0; g2 < 4; ++g2) {
            int d4 = dt * 32 + 8 * g2 + 4 * h;
            s4v ov;
            #pragma unroll
            for (int r = 0; r < 4; ++r) ov[r] = f2bf(O[dt][g2 * 4 + r]);
            *(s4v*)(Opz + (size_t)(q0 + q) * 2048 + head * 128 + d4) = ov;
        }
    if (h == 0)
        stats[((size_t)z * NH + head) * TSEQ + q0 + q] = make_float2(m, lsum);
}

// ---------------------------------------------------------------------------
// Combine the two K-split partials: O = (O0*w0 + O1*w1) / (l0*w0 + l1*w1),
// w_i = exp2(m_i - max(m0,m1)). Block = 16 (row,head) pairs; thread owns 8 d.
// ---------------------------------------------------------------------------
__global__ __launch_bounds__(256) void attn_combine(
    const short* __restrict__ Op0, const short* __restrict__ Op1,
    const float2* __restrict__ stats, short* __restrict__ out)
{
    const int gp = blockIdx.x * 16 + (threadIdx.x >> 4);   // row*16 + head
    const int row = gp >> 4;
    const int head = gp & 15;
    const int d0 = (threadIdx.x & 15) * 8;
    const float2 s0 = stats[(size_t)head * TSEQ + row];
    const float2 s1 = stats[(size_t)(NH + head) * TSEQ + row];
    const float M = fmaxf(s0.x, s1.x);
    const float w0 = exp2f(s0.x - M), w1 = exp2f(s1.x - M);
    const float inv = 1.0f / (s0.y * w0 + s1.y * w1);
    const size_t off = (size_t)row * 2048 + head * 128 + d0;
    s8v a = *(const s8v*)(Op0 + off);
    s8v b = *(const s8v*)(Op1 + off);
    s8v o;
    #pragma unroll
    for (int j = 0; j < 8; ++j)
        o[j] = f2bf((bf2f(a[j]) * w0 + bf2f(b[j]) * w1) * inv);
    *(s8v*)(out + off) = o;
}

// ---------------------------------------------------------------------------
extern "C" void kernel_launch(void* const* d_in, const int* in_sizes, int n_in,
                              void* d_out, int out_size, void* d_ws, size_t ws_size,
                              hipStream_t stream)
{
    const int*   positions = (const int*)  d_in[0];
    const float* hidden    = (const float*)d_in[1];
    const int*   q_qw = (const int*)  d_in[2];
    const float* q_sc = (const float*)d_in[3];
    const int*   q_zr = (const int*)  d_in[4];
    const int*   k_qw = (const int*)  d_in[5];
    const float* k_sc = (const float*)d_in[6];
    const int*   k_zr = (const int*)  d_in[7];
    const int*   v_qw = (const int*)  d_in[8];
    const float* v_sc = (const float*)d_in[9];
    const int*   v_zr = (const int*)  d_in[10];
    const int*   o_qw = (const int*)  d_in[11];
    const float* o_sc = (const float*)d_in[12];
    const int*   o_zr = (const int*)  d_in[13];
    float* outf = (float*)d_out;

    // workspace (40 MB), lifetime-based aliasing:
    //  [0,16M):  qbuf f32[T,2048] (dead after rope)
    //            -> abuf bf16[T,2048] @ [0,8M) (combine out, o-gemm in)
    //            -> Op0 bf16[T,2048] @ [8,16M) (split-0 partial)
    //  [16,20M): kbuf f32[T,512] (dead after rope) -> stats float2[2][NH][T]
    //  [20,28M): hb bf16[2048,2048] (dead after v-gemm) -> Qg bf16[T,2048]
    //  [28,30M): Kg bf16[T,512]
    //  [30,32M): Vtg bf16[512,T]
    //  [32,40M): Op1 bf16[T,2048] (split-1 partial)
    char* base = (char*)d_ws;
    float* qbuf = (float*)(base);
    short* abuf = (short*)(base);
    short* Op0  = (short*)(base + (8u << 20));
    float* kbuf = (float*)(base + (16u << 20));
    float2* stats = (float2*)(base + (16u << 20));
    short* hb   = (short*)(base + (20u << 20));
    short* Qg   = (short*)(base + (20u << 20));
    short* Kg   = (short*)(base + (28u << 20));
    short* Vtg  = (short*)(base + (30u << 20));
    short* Op1  = (short*)(base + (32u << 20));

    dim3 blk(256);
    f32_to_bf16<<<dim3(2048), blk, 0, stream>>>(hidden, hb);
    gemm_gptq_mfma<128, 64, 0><<<dim3(32, 16), blk, 0, stream>>>(hb, q_qw, q_sc, q_zr, qbuf, 2048);
    gemm_gptq_mfma<64, 64, 0><<<dim3(8, 32), blk, 0, stream>>>(hb, k_qw, k_sc, k_zr, kbuf, 512);
    gemm_gptq_mfma<64, 64, 1><<<dim3(8, 32), blk, 0, stream>>>(hb, v_qw, v_sc, v_zr, (void*)Vtg, 512);
    rope_bf16<<<dim3(TSEQ), blk, 0, stream>>>(positions, qbuf, kbuf, Qg, Kg);
    attn32s<<<dim3(64, 4, 2), blk, 0, stream>>>(Qg, Kg, Vtg, Op0, Op1, stats);
    attn_combine<<<dim3(TSEQ * NH / 16), blk, 0, stream>>>(Op0, Op1, stats, abuf);
    gemm_gptq_mfma<128, 64, 0><<<dim3(32, 16), blk, 0, stream>>>(abuf, o_qw, o_sc, o_zr, outf, 2048);
}